// Round 6
// baseline (601.424 us; speedup 1.0000x reference)
//
#include <hip/hip_runtime.h>
#include <hip/hip_fp16.h>

// EnhancedGNN on MI355X.
// R5: T (matmul-out/agg-in intermediate) stored fp16 -> halves the 307MB/layer
//     random gather (k_agg64 was 63us, FETCH 152MB). agg64: 8 edges in flight
//     (8 lanes x 8 feats), grid-stride, fused BN-stats (k_stats deleted).
//     bnscale folded into mm4f/bnmmout prologues. agg2pool: 16 lanes/node.
//     13 launches.

#define NN 100000
#define NE 1200000
#define NBATCH 64
#define IND 128
#define HID 64
#define EPSF 1e-5f
#define NBUCK 782   // ceil(100000/128)
#define NPB 128     // nodes per bucket; bucket(d) = d >> 7
#define AGGGRID 1536

// ---------------- graph prep: bucket histogram ----------------
__global__ void k_ehist(const int* __restrict__ dst, int* __restrict__ gbh) {
  __shared__ int lh[NBUCK];
  int tid = threadIdx.x;
  for (int i = tid; i < NBUCK; i += 256) lh[i] = 0;
  __syncthreads();
  int base = blockIdx.x * 4096;
#pragma unroll
  for (int j = 0; j < 16; j++) {
    int e = base + j * 256 + tid;
    if (e < NE) atomicAdd(&lh[dst[e] >> 7], 1);
  }
  __syncthreads();
  for (int i = tid; i < NBUCK; i += 256) {
    int v = lh[i];
    if (v) atomicAdd(&gbh[i], v);
  }
}

__global__ void k_escan(const int* __restrict__ gbh, int* __restrict__ bbase,
                        int* __restrict__ bcur) {
  __shared__ int a[256];
  int tid = threadIdx.x;
  int loc[4];
  int tsum = 0;
  for (int j = 0; j < 4; j++) {
    int idx = tid * 4 + j;
    int v = (idx < NBUCK) ? gbh[idx] : 0;
    loc[j] = tsum;
    tsum += v;
  }
  a[tid] = tsum;
  __syncthreads();
  for (int off = 1; off < 256; off <<= 1) {
    int v = (tid >= off) ? a[tid - off] : 0;
    __syncthreads();
    a[tid] += v;
    __syncthreads();
  }
  int excl = a[tid] - tsum;
  for (int j = 0; j < 4; j++) {
    int idx = tid * 4 + j;
    if (idx < NBUCK) {
      int v = excl + loc[j];
      bbase[idx] = v;
      bcur[idx] = v;
    }
  }
  if (tid == 255) bbase[NBUCK] = a[255];
}

__global__ void k_escatter(const int* __restrict__ src, const int* __restrict__ dst,
                           int* __restrict__ bcur, unsigned long long* __restrict__ ebuf) {
  __shared__ int lh[NBUCK];
  __shared__ int lbase[NBUCK];
  int tid = threadIdx.x;
  for (int i = tid; i < NBUCK; i += 256) lh[i] = 0;
  __syncthreads();
  int base = blockIdx.x * 4096;
  int sv[16], dv[16], rk[16];
#pragma unroll
  for (int j = 0; j < 16; j++) {
    int e = base + j * 256 + tid;
    if (e < NE) {
      sv[j] = src[e];
      dv[j] = dst[e];
      rk[j] = atomicAdd(&lh[dv[j] >> 7], 1);
    } else {
      dv[j] = -1;
    }
  }
  __syncthreads();
  for (int i = tid; i < NBUCK; i += 256) {
    int v = lh[i];
    lbase[i] = v ? atomicAdd(&bcur[i], v) : 0;
  }
  __syncthreads();
#pragma unroll
  for (int j = 0; j < 16; j++) {
    if (dv[j] >= 0) {
      int b = dv[j] >> 7;
      ebuf[lbase[b] + rk[j]] =
          (unsigned long long)(unsigned)sv[j] | ((unsigned long long)(unsigned)dv[j] << 32);
    }
  }
}

__global__ void k_bucket_csr(const unsigned long long* __restrict__ ebuf,
                             const int* __restrict__ bbase, int* __restrict__ deg,
                             int* __restrict__ rowp, float* __restrict__ dinv,
                             int* __restrict__ col) {
  __shared__ int ldeg[NPB];
  __shared__ int lcur[NPB];
  __shared__ int sred[NPB];
  int b = blockIdx.x, tid = threadIdx.x;
  int nbase = b * NPB;
  int e0 = bbase[b], e1 = bbase[b + 1];
  if (tid < NPB) ldeg[tid] = 0;
  __syncthreads();
  for (int e = e0 + tid; e < e1; e += 256) {
    int d = (int)(ebuf[e] >> 32) - nbase;
    atomicAdd(&ldeg[d], 1);
  }
  __syncthreads();
  if (tid < NPB) sred[tid] = ldeg[tid];
  __syncthreads();
  for (int off = 1; off < NPB; off <<= 1) {
    int v = 0;
    if (tid < NPB && tid >= off) v = sred[tid - off];
    __syncthreads();
    if (tid < NPB) sred[tid] += v;
    __syncthreads();
  }
  if (tid < NPB) {
    int excl = sred[tid] - ldeg[tid];
    lcur[tid] = excl;
    int gn = nbase + tid;
    if (gn < NN) {
      int dg = ldeg[tid];
      deg[gn] = dg;
      rowp[gn] = e0 + excl;
      dinv[gn] = rsqrtf((float)dg + 1.0f);
    }
  }
  __syncthreads();
  for (int e = e0 + tid; e < e1; e += 256) {
    unsigned long long p = ebuf[e];
    int s = (int)(unsigned)p;
    int d = (int)(p >> 32) - nbase;
    int r = atomicAdd(&lcur[d], 1);
    col[e0 + r] = s;
  }
}

// ---------------- helpers ----------------
__device__ inline void store_half8(__half* dst, const float4& a, const float4& b) {
  __half2 h[4];
  h[0] = __floats2half2_rn(a.x, a.y);
  h[1] = __floats2half2_rn(a.z, a.w);
  h[2] = __floats2half2_rn(b.x, b.y);
  h[3] = __floats2half2_rn(b.z, b.w);
  *(float4*)dst = *(float4*)h;
}

// ---------------- dense matmul: X[nrows,K] @ W[K,64] -> T[nrows,64] fp16 ----------------
template <int K>
__global__ void k_mm4(const float* __restrict__ X, const float* __restrict__ W,
                      __half* __restrict__ T, int nrows) {
  __shared__ float Wl[K * 64];
  __shared__ float xs[16][257];
  int tid = threadIdx.x;
#pragma unroll
  for (int i = 0; i < K / 16; i++) {
    int f = i * 256 + tid;
    ((float4*)Wl)[f] = ((const float4*)W)[f];
  }
  int jq = tid & 3;
  int rg = tid >> 2;
  int rbase = blockIdx.x * 256;
  float4 acc[4][4];
#pragma unroll
  for (int m = 0; m < 4; m++)
#pragma unroll
    for (int q = 0; q < 4; q++) acc[m][q] = {0.f, 0.f, 0.f, 0.f};

  for (int c = 0; c < K / 16; c++) {
#pragma unroll
    for (int i = 0; i < 4; i++) {
      int f = i * 256 + tid;
      int r = f >> 2, kq = f & 3;
      int gr = rbase + r;
      int grc = gr < nrows ? gr : nrows - 1;
      float4 v = *(const float4*)(X + (size_t)grc * K + c * 16 + 4 * kq);
      xs[4 * kq + 0][r] = v.x;
      xs[4 * kq + 1][r] = v.y;
      xs[4 * kq + 2][r] = v.z;
      xs[4 * kq + 3][r] = v.w;
    }
    __syncthreads();
    const float* Wc = Wl + c * 16 * 64 + jq * 16;
#pragma unroll
    for (int kk = 0; kk < 16; kk++) {
      float4 wq[4];
      wq[0] = *(const float4*)(Wc + kk * 64 + 0);
      wq[1] = *(const float4*)(Wc + kk * 64 + 4);
      wq[2] = *(const float4*)(Wc + kk * 64 + 8);
      wq[3] = *(const float4*)(Wc + kk * 64 + 12);
      float xm[4];
      xm[0] = xs[kk][rg];
      xm[1] = xs[kk][rg + 64];
      xm[2] = xs[kk][rg + 128];
      xm[3] = xs[kk][rg + 192];
#pragma unroll
      for (int m = 0; m < 4; m++)
#pragma unroll
        for (int q = 0; q < 4; q++) {
          acc[m][q].x = fmaf(xm[m], wq[q].x, acc[m][q].x);
          acc[m][q].y = fmaf(xm[m], wq[q].y, acc[m][q].y);
          acc[m][q].z = fmaf(xm[m], wq[q].z, acc[m][q].z);
          acc[m][q].w = fmaf(xm[m], wq[q].w, acc[m][q].w);
        }
    }
    __syncthreads();
  }

#pragma unroll
  for (int m = 0; m < 4; m++) {
    int row = rbase + rg + 64 * m;
    if (row < nrows) {
      store_half8(T + (size_t)row * 64 + jq * 16, acc[m][0], acc[m][1]);
      store_half8(T + (size_t)row * 64 + jq * 16 + 8, acc[m][2], acc[m][3]);
    }
  }
}

// fused: compute BN scale from stats; h = BN(G)(+res) during staging; side-write h;
// T = h @ W stored fp16
__global__ void k_mm4f(const float* __restrict__ G, const double* __restrict__ st,
                       const float* __restrict__ gamma, const float* __restrict__ beta,
                       const float* __restrict__ res, float* __restrict__ Hside,
                       const float* __restrict__ W, __half* __restrict__ T, int nrows) {
  __shared__ float Wl[64 * 64];
  __shared__ float xs[16][257];
  __shared__ float scl[128];
  int tid = threadIdx.x;
#pragma unroll
  for (int i = 0; i < 4; i++) {
    int f = i * 256 + tid;
    ((float4*)Wl)[f] = ((const float4*)W)[f];
  }
  if (tid < 64) {
    double m = st[tid] / (double)NN;
    double var = st[64 + tid] / (double)NN - m * m;
    float scale = gamma[tid] * rsqrtf((float)var + EPSF);
    scl[tid] = scale;
    scl[64 + tid] = beta[tid] - (float)m * scale;
  }
  __syncthreads();
  int jq = tid & 3;
  int rg = tid >> 2;
  int rbase = blockIdx.x * 256;
  float4 acc[4][4];
#pragma unroll
  for (int m = 0; m < 4; m++)
#pragma unroll
    for (int q = 0; q < 4; q++) acc[m][q] = {0.f, 0.f, 0.f, 0.f};

  for (int c = 0; c < 4; c++) {
#pragma unroll
    for (int i = 0; i < 4; i++) {
      int f = i * 256 + tid;
      int r = f >> 2, kq = f & 3;
      int gr = rbase + r;
      int grc = gr < nrows ? gr : nrows - 1;
      int kof = c * 16 + 4 * kq;
      float4 v = *(const float4*)(G + (size_t)grc * 64 + kof);
      float4 s = ((const float4*)scl)[kof >> 2];
      float4 sh = ((const float4*)(scl + 64))[kof >> 2];
      v.x = v.x * s.x + sh.x;
      v.y = v.y * s.y + sh.y;
      v.z = v.z * s.z + sh.z;
      v.w = v.w * s.w + sh.w;
      if (res != nullptr) {
        float4 rr = *(const float4*)(res + (size_t)grc * 64 + kof);
        v.x += rr.x; v.y += rr.y; v.z += rr.z; v.w += rr.w;
      }
      if (gr < nrows) *(float4*)(Hside + (size_t)gr * 64 + kof) = v;
      xs[4 * kq + 0][r] = v.x;
      xs[4 * kq + 1][r] = v.y;
      xs[4 * kq + 2][r] = v.z;
      xs[4 * kq + 3][r] = v.w;
    }
    __syncthreads();
    const float* Wc = Wl + c * 16 * 64 + jq * 16;
#pragma unroll
    for (int kk = 0; kk < 16; kk++) {
      float4 wq[4];
      wq[0] = *(const float4*)(Wc + kk * 64 + 0);
      wq[1] = *(const float4*)(Wc + kk * 64 + 4);
      wq[2] = *(const float4*)(Wc + kk * 64 + 8);
      wq[3] = *(const float4*)(Wc + kk * 64 + 12);
      float xm[4];
      xm[0] = xs[kk][rg];
      xm[1] = xs[kk][rg + 64];
      xm[2] = xs[kk][rg + 128];
      xm[3] = xs[kk][rg + 192];
#pragma unroll
      for (int m = 0; m < 4; m++)
#pragma unroll
        for (int q = 0; q < 4; q++) {
          acc[m][q].x = fmaf(xm[m], wq[q].x, acc[m][q].x);
          acc[m][q].y = fmaf(xm[m], wq[q].y, acc[m][q].y);
          acc[m][q].z = fmaf(xm[m], wq[q].z, acc[m][q].z);
          acc[m][q].w = fmaf(xm[m], wq[q].w, acc[m][q].w);
        }
    }
    __syncthreads();
  }

#pragma unroll
  for (int m = 0; m < 4; m++) {
    int row = rbase + rg + 64 * m;
    if (row < nrows) {
      store_half8(T + (size_t)row * 64 + jq * 16, acc[m][0], acc[m][1]);
      store_half8(T + (size_t)row * 64 + jq * 16 + 8, acc[m][2], acc[m][3]);
    }
  }
}

// ---------------- aggregation (HID=64) + relu + fused BN stats ----------------
// wave per node (grid-stride): 8 edges in flight x 8 lanes x 8 feats (fp16 gather).
__global__ void k_agg64s(const __half* __restrict__ T, const int* __restrict__ rowp,
                         const int* __restrict__ deg, const int* __restrict__ col,
                         const float* __restrict__ dinv, const float* __restrict__ bias,
                         float* __restrict__ G, double* __restrict__ st) {
  int tid = threadIdx.x;
  int lane = tid & 63;
  int wv = tid >> 6;
  int grp = lane >> 3;  // edge slot 0..7
  int q = lane & 7;     // feature octet: feats 8q..8q+7
  float s1[8], s2[8];
#pragma unroll
  for (int k = 0; k < 8; k++) { s1[k] = 0.f; s2[k] = 0.f; }

  for (int node = blockIdx.x * 4 + wv; node < NN; node += AGGGRID * 4) {
    int s = rowp[node];
    int c = deg[node];
    float acc[8];
#pragma unroll
    for (int k = 0; k < 8; k++) acc[k] = 0.f;
    for (int i = 0; i < c; i += 8) {
      int j = i + grp;
      if (j < c) {
        int src = col[s + j];
        float dv = dinv[src];
        float4 raw = *(const float4*)(T + (size_t)src * 64 + q * 8);
        const __half2* h2 = (const __half2*)&raw;
#pragma unroll
        for (int k = 0; k < 4; k++) {
          float2 f = __half22float2(h2[k]);
          acc[2 * k] = fmaf(f.x, dv, acc[2 * k]);
          acc[2 * k + 1] = fmaf(f.y, dv, acc[2 * k + 1]);
        }
      }
    }
#pragma unroll
    for (int k = 0; k < 8; k++) {
      acc[k] += __shfl_xor(acc[k], 8, 64);
      acc[k] += __shfl_xor(acc[k], 16, 64);
      acc[k] += __shfl_xor(acc[k], 32, 64);
    }
    if (grp == 0) {
      float di = dinv[node];
      float dd = di * di;
      float4 raw = *(const float4*)(T + (size_t)node * 64 + q * 8);
      const __half2* h2 = (const __half2*)&raw;
      float4 b0 = *(const float4*)(bias + q * 8);
      float4 b1 = *(const float4*)(bias + q * 8 + 4);
      float bb[8] = {b0.x, b0.y, b0.z, b0.w, b1.x, b1.y, b1.z, b1.w};
      float o[8];
#pragma unroll
      for (int k = 0; k < 4; k++) {
        float2 f = __half22float2(h2[k]);
        o[2 * k] = fmaxf(acc[2 * k] * di + f.x * dd + bb[2 * k], 0.f);
        o[2 * k + 1] = fmaxf(acc[2 * k + 1] * di + f.y * dd + bb[2 * k + 1], 0.f);
      }
      float4 o0 = {o[0], o[1], o[2], o[3]};
      float4 o1 = {o[4], o[5], o[6], o[7]};
      *(float4*)(G + (size_t)node * 64 + q * 8) = o0;
      *(float4*)(G + (size_t)node * 64 + q * 8 + 4) = o1;
#pragma unroll
      for (int k = 0; k < 8; k++) {
        s1[k] += o[k];
        s2[k] = fmaf(o[k], o[k], s2[k]);
      }
    }
  }
  // stats: per-wave grp==0 lanes hold feats q*8+k
  __shared__ float sd[4][128];
  if (grp == 0) {
#pragma unroll
    for (int k = 0; k < 8; k++) {
      sd[wv][q * 8 + k] = s1[k];
      sd[wv][64 + q * 8 + k] = s2[k];
    }
  }
  __syncthreads();
  if (tid < 128) {
    float t = sd[0][tid] + sd[1][tid] + sd[2][tid] + sd[3][tid];
    unsafeAtomicAdd(&st[tid], (double)t);
  }
}

// ---------------- fused: BN3(from stats) + residual + matmul 64->2 ----------------
__global__ void k_bnmmout(const float* __restrict__ G, const double* __restrict__ st,
                          const float* __restrict__ gamma, const float* __restrict__ beta,
                          const float* __restrict__ res, const float* __restrict__ W,
                          float* __restrict__ T2, int nrows) {
  __shared__ float Wl[128];
  __shared__ float scl[128];
  int tid = threadIdx.x;
  if (tid < 32) ((float4*)Wl)[tid] = ((const float4*)W)[tid];
  if (tid < 64) {
    double m = st[tid] / (double)NN;
    double var = st[64 + tid] / (double)NN - m * m;
    float scale = gamma[tid] * rsqrtf((float)var + EPSF);
    scl[tid] = scale;
    scl[64 + tid] = beta[tid] - (float)m * scale;
  }
  __syncthreads();
  int row = blockIdx.x * 256 + tid;
  if (row >= nrows) return;
  const float4* g4 = (const float4*)(G + (size_t)row * 64);
  const float4* r4 = (const float4*)(res + (size_t)row * 64);
  float a0 = 0.f, a1 = 0.f;
#pragma unroll
  for (int q = 0; q < 16; q++) {
    float4 v = g4[q];
    float4 rr = r4[q];
    float4 s = ((const float4*)scl)[q];
    float4 sh = ((const float4*)(scl + 64))[q];
    float h0 = v.x * s.x + sh.x + rr.x;
    float h1 = v.y * s.y + sh.y + rr.y;
    float h2 = v.z * s.z + sh.z + rr.z;
    float h3 = v.w * s.w + sh.w + rr.w;
    const float* wk = Wl + q * 8;
    a0 = fmaf(h0, wk[0], a0); a1 = fmaf(h0, wk[1], a1);
    a0 = fmaf(h1, wk[2], a0); a1 = fmaf(h1, wk[3], a1);
    a0 = fmaf(h2, wk[4], a0); a1 = fmaf(h2, wk[5], a1);
    a0 = fmaf(h3, wk[6], a0); a1 = fmaf(h3, wk[7], a1);
  }
  T2[(size_t)row * 2 + 0] = a0;
  T2[(size_t)row * 2 + 1] = a1;
}

// ---------------- fused final aggregation (dim 2) + segment mean pool ----------------
// 16 lanes per node, 16 edges in flight.
__global__ void k_agg2pool(const float* __restrict__ T2, const int* __restrict__ rowp,
                           const int* __restrict__ deg, const int* __restrict__ col,
                           const float* __restrict__ dinv, const float* __restrict__ bias,
                           const int* __restrict__ batch, float* __restrict__ pool,
                           int* __restrict__ pcnt) {
  __shared__ float pl[128];
  __shared__ int pc[64];
  int tid = threadIdx.x;
  if (tid < 128) pl[tid] = 0.f;
  if (tid < 64) pc[tid] = 0;
  __syncthreads();
  int lane = tid & 63;
  int wv = tid >> 6;
  int grp = lane >> 4;  // node slot in wave
  int l16 = lane & 15;
  int node = blockIdx.x * 16 + wv * 4 + grp;
  float a0 = 0.f, a1 = 0.f;
  if (node < NN) {
    int s = rowp[node];
    int c = deg[node];
    for (int i = l16; i < c; i += 16) {
      int sr = col[s + i];
      float dv = dinv[sr];
      float2 t = *(const float2*)(T2 + (size_t)sr * 2);
      a0 = fmaf(t.x, dv, a0);
      a1 = fmaf(t.y, dv, a1);
    }
  }
#pragma unroll
  for (int off = 1; off < 16; off <<= 1) {
    a0 += __shfl_xor(a0, off, 64);
    a1 += __shfl_xor(a1, off, 64);
  }
  if (node < NN && l16 == 0) {
    float di = dinv[node];
    float dd = di * di;
    float2 t = *(const float2*)(T2 + (size_t)node * 2);
    float v0 = a0 * di + t.x * dd + bias[0];
    float v1 = a1 * di + t.y * dd + bias[1];
    int b = batch[node];
    atomicAdd(&pl[b * 2 + 0], v0);
    atomicAdd(&pl[b * 2 + 1], v1);
    atomicAdd(&pc[b], 1);
  }
  __syncthreads();
  if (tid < 128 && pl[tid] != 0.f) unsafeAtomicAdd(&pool[tid], pl[tid]);
  if (tid < 64 && pc[tid] != 0) atomicAdd(&pcnt[tid], pc[tid]);
}

__global__ void k_div(const float* __restrict__ pool, const int* __restrict__ pcnt,
                      float* __restrict__ out) {
  int i = threadIdx.x;
  if (i < 128) {
    int c = pcnt[i >> 1];
    out[i] = pool[i] / (float)(c > 0 ? c : 1);
  }
}

extern "C" void kernel_launch(void* const* d_in, const int* in_sizes, int n_in,
                              void* d_out, int out_size, void* d_ws, size_t ws_size,
                              hipStream_t stream) {
  (void)in_sizes; (void)n_in; (void)out_size; (void)ws_size;
  const float* x     = (const float*)d_in[0];
  const float* W_in  = (const float*)d_in[1];
  const float* b_in  = (const float*)d_in[2];
  const float* W_h   = (const float*)d_in[3];
  const float* b_h   = (const float*)d_in[4];
  const float* W_out = (const float*)d_in[5];
  const float* b_out = (const float*)d_in[6];
  const float* gamma = (const float*)d_in[7];
  const float* beta  = (const float*)d_in[8];
  const int*   ei    = (const int*)d_in[9];
  const int*   batch = (const int*)d_in[10];
  const int* src = ei;
  const int* dst = ei + NE;
  float* out = (float*)d_out;

  char* w = (char*)d_ws;
  size_t off = 0;
  auto alloc = [&](size_t bytes) -> void* {
    void* p = (void*)(w + off);
    off += (bytes + 511) & ~(size_t)511;
    return p;
  };
  int*    deg   = (int*)alloc((size_t)NN * 4);
  int*    rowp  = (int*)alloc((size_t)NN * 4);
  int*    col   = (int*)alloc((size_t)NE * 4);
  float*  dinv  = (float*)alloc((size_t)NN * 4);
  int*    bbase = (int*)alloc((NBUCK + 1) * 4);
  int*    bcur  = (int*)alloc(NBUCK * 4);
  // zeroed zone: stats (3*128 dbl) | pool (512B) | pcnt (256B) | gbh (782*4)
  char*   zzone = (char*)alloc(7168);
  double* stats = (double*)zzone;
  float*  pool  = (float*)(zzone + 3072);
  int*    pcnt  = (int*)(zzone + 3072 + 512);
  int*    gbh   = (int*)(zzone + 3840);
  __half* Th    = (__half*)alloc((size_t)NN * HID * 2);
  float*  buf0  = (float*)alloc((size_t)NN * HID * 4);
  float*  buf1  = (float*)alloc((size_t)NN * HID * 4);
  float*  buf2  = (float*)alloc((size_t)NN * HID * 4);
  float*  T2    = (float*)alloc((size_t)NN * 2 * 4);
  // ebuf (9.6MB) aliases buf0: consumed by k_bucket_csr before buf0's first write (L3 mm4f)
  unsigned long long* ebuf = (unsigned long long*)buf0;

  hipMemsetAsync(zzone, 0, 7040, stream);

  // graph prep: bucket-radix CSR build
  k_ehist<<<293, 256, 0, stream>>>(dst, gbh);
  k_escan<<<1, 256, 0, stream>>>(gbh, bbase, bcur);
  k_escatter<<<293, 256, 0, stream>>>(src, dst, bcur, ebuf);
  k_bucket_csr<<<NBUCK, 256, 0, stream>>>(ebuf, bbase, deg, rowp, dinv, col);

  const int mmgrid = (NN + 255) / 256;  // 391

  // layer 1: T1 = x @ W_in (fp16); G1 = agg(T1) -> buf1 (+stats0)
  k_mm4<IND><<<mmgrid, 256, 0, stream>>>(x, W_in, Th, NN);
  k_agg64s<<<AGGGRID, 256, 0, stream>>>(Th, rowp, deg, col, dinv, b_in, buf1, stats);

  // layer 2: h1 = BN0(G1) (side->buf2); T = h1@W_h0 (fp16); G2 = agg -> buf1 (+stats1)
  k_mm4f<<<mmgrid, 256, 0, stream>>>(buf1, stats, gamma, beta, nullptr, buf2, W_h, Th, NN);
  k_agg64s<<<AGGGRID, 256, 0, stream>>>(Th, rowp, deg, col, dinv, b_h, buf1, stats + 128);

  // layer 3: h2 = BN1(G2)+h1 (side->buf0); T = h2@W_h1; G3 = agg -> buf2 (+stats2)
  k_mm4f<<<mmgrid, 256, 0, stream>>>(buf1, stats + 128, gamma + 64, beta + 64, buf2, buf0,
                                     W_h + HID * HID, Th, NN);
  k_agg64s<<<AGGGRID, 256, 0, stream>>>(Th, rowp, deg, col, dinv, b_h + HID, buf2, stats + 256);

  // output: h3 = BN2(G3)+h2 fused with mm 64->2, then agg+pool fused
  k_bnmmout<<<mmgrid, 256, 0, stream>>>(buf2, stats + 256, gamma + 128, beta + 128, buf0,
                                        W_out, T2, NN);
  k_agg2pool<<<(NN + 15) / 16, 256, 0, stream>>>(T2, rowp, deg, col, dinv, b_out, batch,
                                                 pool, pcnt);
  k_div<<<1, 128, 0, stream>>>(pool, pcnt, out);
}